// Round 8
// baseline (766.180 us; speedup 1.0000x reference)
//
#include <hip/hip_runtime.h>
#include <hip/hip_bf16.h>

#define NQ 20000
#define NKV 20000
#define NE 640000
#define DD 128
#define HH 128

typedef short bf16x8 __attribute__((ext_vector_type(8)));
typedef float f32x4 __attribute__((ext_vector_type(4)));

static __device__ __forceinline__ unsigned short f2b(float f) {
  unsigned u = __builtin_bit_cast(unsigned, f);
  u += 0x7fffu + ((u >> 16) & 1u);  // RNE
  return (unsigned short)(u >> 16);
}
static __device__ __forceinline__ float silu_f(float x) {
  return x / (1.0f + __expf(-x));
}

constexpr int BM  = 64;   // edges (or nodes) per workgroup tile
constexpr int LDA = 264;  // 256 + 8 pad (bf16 elems)
constexpr int LDT = 136;  // 128 + 8 pad
constexpr int NCH = (NQ + 255) / 256;  // 79 scan chunks

// Convert 8 consecutive floats -> 8 bf16 packed in a uint4
static __device__ __forceinline__ uint4 pack8(const float4* s4) {
  float4 a = s4[0], b = s4[1];
  union { unsigned short u[8]; uint4 q; } p;
  p.u[0] = f2b(a.x); p.u[1] = f2b(a.y); p.u[2] = f2b(a.z); p.u[3] = f2b(a.w);
  p.u[4] = f2b(b.x); p.u[5] = f2b(b.y); p.u[6] = f2b(b.z); p.u[7] = f2b(b.w);
  return p.q;
}

// ============ one-time fp32 -> bf16 conversion of node features ============
__global__ __launch_bounds__(256) void conv_kernel(const float* __restrict__ src,
                                                   unsigned short* __restrict__ dst,
                                                   int n8) {
  const int i = blockIdx.x * 256 + threadIdx.x;
  if (i < n8) ((uint4*)dst)[i] = pack8(((const float4*)src) + 2 * i);
}

// ================= CSR build: histogram -> scan -> scatter =================
__global__ __launch_bounds__(256) void hist_kernel(const int* __restrict__ erow,
                                                   int* __restrict__ cnt) {
  const int i = blockIdx.x * 256 + threadIdx.x;
  if (i < NE) atomicAdd(&cnt[erow[i]], 1);
}

// Hierarchical exclusive scan over NQ counts (3 parallel phases).
__global__ __launch_bounds__(256) void scan1_kernel(const int* __restrict__ cnt,
                                                    int* __restrict__ offs,
                                                    int* __restrict__ blksum) {
  __shared__ int s[256];
  const int tid = threadIdx.x;
  const int idx = blockIdx.x * 256 + tid;
  const int v = (idx < NQ) ? cnt[idx] : 0;
  s[tid] = v;
  __syncthreads();
#pragma unroll
  for (int off = 1; off < 256; off <<= 1) {
    const int t = (tid >= off) ? s[tid - off] : 0;
    __syncthreads();
    s[tid] += t;
    __syncthreads();
  }
  if (idx < NQ) offs[idx] = s[tid] - v;  // exclusive within chunk
  if (tid == 255) blksum[blockIdx.x] = s[255];
}

__global__ __launch_bounds__(128) void scan2_kernel(const int* __restrict__ blksum,
                                                    int* __restrict__ blkoff,
                                                    int* __restrict__ offs) {
  __shared__ int s[128];
  const int tid = threadIdx.x;
  const int v = (tid < NCH) ? blksum[tid] : 0;
  s[tid] = v;
  __syncthreads();
#pragma unroll
  for (int off = 1; off < 128; off <<= 1) {
    const int t = (tid >= off) ? s[tid - off] : 0;
    __syncthreads();
    s[tid] += t;
    __syncthreads();
  }
  if (tid < NCH) blkoff[tid] = s[tid] - v;
  if (tid == 127) offs[NQ] = s[127];  // grand total (entries >= NCH are 0)
}

__global__ __launch_bounds__(256) void scan3_kernel(int* __restrict__ offs,
                                                    int* __restrict__ cur,
                                                    const int* __restrict__ blkoff) {
  const int idx = blockIdx.x * 256 + threadIdx.x;
  if (idx < NQ) {
    const int o = offs[idx] + blkoff[blockIdx.x];
    offs[idx] = o;
    cur[idx] = o;
  }
}

__global__ __launch_bounds__(256) void scatter_kernel(const int* __restrict__ erow,
                                                      int* __restrict__ cur,
                                                      int* __restrict__ eid) {
  const int i = blockIdx.x * 256 + threadIdx.x;
  if (i < NE) {
    const int p = atomicAdd(&cur[erow[i]], 1);
    eid[p] = i;
  }
}

// ============ deterministic aggregation: one wave per query row ============
// 4-way unroll: 4 independent 512B row gathers in flight per wave.
__global__ __launch_bounds__(256) void agg_kernel(const float* __restrict__ mij,
                                                  const int* __restrict__ offs,
                                                  const int* __restrict__ eid,
                                                  float* __restrict__ agg) {
  const int w = (blockIdx.x * 256 + threadIdx.x) >> 6;  // wave id = row
  const int lane = threadIdx.x & 63;
  if (w >= NQ) return;
  const int s = offs[w];
  const int e = offs[w + 1];
  float2 a0 = {0.0f, 0.0f};
  float2 a1 = {0.0f, 0.0f};
  float2 a2 = {0.0f, 0.0f};
  float2 a3 = {0.0f, 0.0f};
  int i = s;
  for (; i + 4 <= e; i += 4) {
    const int e0 = eid[i];
    const int e1 = eid[i + 1];
    const int e2 = eid[i + 2];
    const int e3 = eid[i + 3];
    const float2 v0 = ((const float2*)(mij + (size_t)e0 * HH))[lane];
    const float2 v1 = ((const float2*)(mij + (size_t)e1 * HH))[lane];
    const float2 v2 = ((const float2*)(mij + (size_t)e2 * HH))[lane];
    const float2 v3 = ((const float2*)(mij + (size_t)e3 * HH))[lane];
    a0.x += v0.x; a0.y += v0.y;
    a1.x += v1.x; a1.y += v1.y;
    a2.x += v2.x; a2.y += v2.y;
    a3.x += v3.x; a3.y += v3.y;
  }
  for (; i < e; ++i) {
    const int e0 = eid[i];
    const float2 v0 = ((const float2*)(mij + (size_t)e0 * HH))[lane];
    a0.x += v0.x; a0.y += v0.y;
  }
  a0.x += a1.x; a0.y += a1.y;
  a2.x += a3.x; a2.y += a3.y;
  a0.x += a2.x; a0.y += a2.y;
  ((float2*)(agg + (size_t)w * HH))[lane] = a0;
}

// ---------------- edge kernel: mij = silu(silu([hq|hkv]@We1+be1)@We2+be2)
//   PRECONV: gather pre-converted bf16 rows, REGISTER-PREFETCHED one tile
//            ahead (T14 async-STAGE split: gather latency hides under MFMA)
//   DO_ATOMIC: also agg[row] += mij via fp32 atomics (fallback path)
//   launch_bounds(256,3): LDS 51.5KB*3 = 154.4KB <= 160KB -> 3 blocks/CU
template <bool PRECONV, bool DO_ATOMIC>
__global__ __launch_bounds__(256, 3) void edge_kernel(
    const float* __restrict__ h_q,
    const float* __restrict__ h_kv,
    const unsigned short* __restrict__ hqb,
    const unsigned short* __restrict__ hkvb,
    const int* __restrict__ erow,
    const int* __restrict__ ecol,
    const float* __restrict__ We1,
    const float* __restrict__ be1,
    const float* __restrict__ We2,
    const float* __restrict__ be2,
    float* __restrict__ mij,
    float* __restrict__ agg,
    int num_tiles) {
  __shared__ __align__(16) unsigned short sA[BM * LDA];
  __shared__ __align__(16) unsigned short sT[BM * LDT];
  __shared__ int sRow[BM];

  const int tid  = threadIdx.x;
  const int wave = tid >> 6;
  const int lane = tid & 63;
  const int quad = lane >> 4;
  const int l16  = lane & 15;
  const int wcol = wave * 32;  // this wave's 32-column strip

  // ---- persistent weight B-fragments: B[k][n], n=l16, k=quad*8+j ----
  bf16x8 wf1[2][8];
  bf16x8 wf2[2][4];
  float bias1[2], bias2[2];
#pragma unroll
  for (int nt = 0; nt < 2; ++nt) {
    const int n = wcol + nt * 16 + l16;
    bias1[nt] = be1[n];
    bias2[nt] = be2[n];
#pragma unroll
    for (int ks = 0; ks < 8; ++ks) {
      const int kb = ks * 32 + quad * 8;
      bf16x8 v;
#pragma unroll
      for (int j = 0; j < 8; ++j) v[j] = (short)f2b(We1[(kb + j) * HH + n]);
      wf1[nt][ks] = v;
    }
#pragma unroll
    for (int ks = 0; ks < 4; ++ks) {
      const int kb = ks * 32 + quad * 8;
      bf16x8 v;
#pragma unroll
      for (int j = 0; j < 8; ++j) v[j] = (short)f2b(We2[(kb + j) * HH + n]);
      wf2[nt][ks] = v;
    }
  }

  const int el = tid >> 2;    // edge-in-tile this thread stages
  const int part = tid & 3;   // which 64-elem quarter of the 256-col row

  // ---- PRECONV: prefetch tile 0's gather into registers ----
  uint4 pf[8];
  int prow = 0;
  if (PRECONV && blockIdx.x < num_tiles) {
    const int e = blockIdx.x * BM + el;
    prow = erow[e];
    const int pcol = ecol[e];
    const unsigned short* src =
        (part < 2 ? hqb + (size_t)prow * DD : hkvb + (size_t)pcol * DD) + (part & 1) * 64;
    const uint4* s4 = (const uint4*)src;
#pragma unroll
    for (int i = 0; i < 8; ++i) pf[i] = s4[i];
  }

  for (int tile = blockIdx.x; tile < num_tiles; tile += gridDim.x) {
    const int e0 = tile * BM;

    // ---- stage current tile ----
    {
      uint4* d4 = (uint4*)(sA + el * LDA + part * 64);
      if (PRECONV) {
        if (part == 0) sRow[el] = prow;
#pragma unroll
        for (int i = 0; i < 8; ++i) d4[i] = pf[i];
      } else {
        const int e = e0 + el;
        const int r = erow[e];
        const int c = ecol[e];
        if (part == 0) sRow[el] = r;
        const float* src =
            (part < 2 ? h_q + (size_t)r * DD : h_kv + (size_t)c * DD) + (part & 1) * 64;
        const float4* s4 = (const float4*)src;
#pragma unroll
        for (int i = 0; i < 8; ++i) d4[i] = pack8(s4 + 2 * i);
      }
    }
    __syncthreads();

    // ---- PRECONV: issue next tile's gather now; completes under compute ----
    if (PRECONV) {
      const int next = tile + gridDim.x;
      if (next < num_tiles) {
        const int e = next * BM + el;
        prow = erow[e];
        const int pcol = ecol[e];
        const unsigned short* src =
            (part < 2 ? hqb + (size_t)prow * DD : hkvb + (size_t)pcol * DD) + (part & 1) * 64;
        const uint4* s4 = (const uint4*)src;
#pragma unroll
        for (int i = 0; i < 8; ++i) pf[i] = s4[i];
      }
    }

    // ---- layer 1: [64x256] @ We1 ----
    f32x4 acc[4][2];
#pragma unroll
    for (int mt = 0; mt < 4; ++mt)
#pragma unroll
      for (int nt = 0; nt < 2; ++nt) {
        f32x4 z = {0.0f, 0.0f, 0.0f, 0.0f};
        acc[mt][nt] = z;
      }
#pragma unroll
    for (int ks = 0; ks < 8; ++ks) {
#pragma unroll
      for (int mt = 0; mt < 4; ++mt) {
        bf16x8 a = *(const bf16x8*)(sA + (mt * 16 + l16) * LDA + ks * 32 + quad * 8);
        acc[mt][0] = __builtin_amdgcn_mfma_f32_16x16x32_bf16(a, wf1[0][ks], acc[mt][0], 0, 0, 0);
        acc[mt][1] = __builtin_amdgcn_mfma_f32_16x16x32_bf16(a, wf1[1][ks], acc[mt][1], 0, 0, 0);
      }
    }

    // ---- silu -> sT (C-layout: col=l16, row=quad*4+rg) ----
#pragma unroll
    for (int mt = 0; mt < 4; ++mt)
#pragma unroll
      for (int nt = 0; nt < 2; ++nt)
#pragma unroll
        for (int rg = 0; rg < 4; ++rg) {
          float x = silu_f(acc[mt][nt][rg] + bias1[nt]);
          sT[(mt * 16 + quad * 4 + rg) * LDT + wcol + nt * 16 + l16] = f2b(x);
        }
    __syncthreads();

    // ---- layer 2: [64x128] @ We2 ----
    f32x4 acc2[4][2];
#pragma unroll
    for (int mt = 0; mt < 4; ++mt)
#pragma unroll
      for (int nt = 0; nt < 2; ++nt) {
        f32x4 z = {0.0f, 0.0f, 0.0f, 0.0f};
        acc2[mt][nt] = z;
      }
#pragma unroll
    for (int ks = 0; ks < 4; ++ks) {
#pragma unroll
      for (int mt = 0; mt < 4; ++mt) {
        bf16x8 a = *(const bf16x8*)(sT + (mt * 16 + l16) * LDT + ks * 32 + quad * 8);
        acc2[mt][0] = __builtin_amdgcn_mfma_f32_16x16x32_bf16(a, wf2[0][ks], acc2[mt][0], 0, 0, 0);
        acc2[mt][1] = __builtin_amdgcn_mfma_f32_16x16x32_bf16(a, wf2[1][ks], acc2[mt][1], 0, 0, 0);
      }
    }

    // ---- epilogue: mij store (fp32); atomic scatter only in fallback ----
#pragma unroll
    for (int mt = 0; mt < 4; ++mt) {
#pragma unroll
      for (int rg = 0; rg < 4; ++rg) {
        const int m = mt * 16 + quad * 4 + rg;
        const size_t e = (size_t)(e0 + m);
        const int gr = sRow[m];
#pragma unroll
        for (int nt = 0; nt < 2; ++nt) {
          const int n = wcol + nt * 16 + l16;
          float x = silu_f(acc2[mt][nt][rg] + bias2[nt]);
          mij[e * HH + n] = x;
          if (DO_ATOMIC) atomicAdd(&agg[(size_t)gr * HH + n], x);
        }
      }
    }
    __syncthreads();  // protect sA/sRow/sT against next iteration's staging
  }
}

// ---------------- node kernel: out = h_q + silu([h_q|agg]@Wn1+bn1)@Wn2+bn2 ----
__global__ __launch_bounds__(256, 2) void node_kernel(
    const float* __restrict__ h_q,
    const float* __restrict__ agg,
    const float* __restrict__ Wn1,
    const float* __restrict__ bn1,
    const float* __restrict__ Wn2,
    const float* __restrict__ bn2,
    float* __restrict__ out,
    int num_tiles) {
  __shared__ __align__(16) unsigned short sA[BM * LDA];
  __shared__ __align__(16) unsigned short sT[BM * LDT];

  const int tid  = threadIdx.x;
  const int wave = tid >> 6;
  const int lane = tid & 63;
  const int quad = lane >> 4;
  const int l16  = lane & 15;
  const int wcol = wave * 32;

  bf16x8 wf1[2][8];
  bf16x8 wf2[2][4];
  float bias1[2], bias2[2];
#pragma unroll
  for (int nt = 0; nt < 2; ++nt) {
    const int n = wcol + nt * 16 + l16;
    bias1[nt] = bn1[n];
    bias2[nt] = bn2[n];
#pragma unroll
    for (int ks = 0; ks < 8; ++ks) {
      const int kb = ks * 32 + quad * 8;
      bf16x8 v;
#pragma unroll
      for (int j = 0; j < 8; ++j) v[j] = (short)f2b(Wn1[(kb + j) * HH + n]);
      wf1[nt][ks] = v;
    }
#pragma unroll
    for (int ks = 0; ks < 4; ++ks) {
      const int kb = ks * 32 + quad * 8;
      bf16x8 v;
#pragma unroll
      for (int j = 0; j < 8; ++j) v[j] = (short)f2b(Wn2[(kb + j) * HH + n]);
      wf2[nt][ks] = v;
    }
  }

  for (int tile = blockIdx.x; tile < num_tiles; tile += gridDim.x) {
    const int n0 = tile * BM;

    // ---- stage: parts 0/1 = h_q, parts 2/3 = agg (both fp32 -> bf16) ----
    {
      const int el = tid >> 2;
      const int part = tid & 3;
      const int node = n0 + el;
      uint4* d4 = (uint4*)(sA + el * LDA + part * 64);
      if (node < NQ) {
        const float* src =
            (part < 2 ? h_q + (size_t)node * DD : agg + (size_t)node * HH) + (part & 1) * 64;
        const float4* s4 = (const float4*)src;
#pragma unroll
        for (int i = 0; i < 8; ++i) d4[i] = pack8(s4 + 2 * i);
      } else {
        uint4 z = {0u, 0u, 0u, 0u};
#pragma unroll
        for (int i = 0; i < 8; ++i) d4[i] = z;
      }
    }
    __syncthreads();

    f32x4 acc[4][2];
#pragma unroll
    for (int mt = 0; mt < 4; ++mt)
#pragma unroll
      for (int nt = 0; nt < 2; ++nt) {
        f32x4 z = {0.0f, 0.0f, 0.0f, 0.0f};
        acc[mt][nt] = z;
      }
#pragma unroll
    for (int ks = 0; ks < 8; ++ks) {
#pragma unroll
      for (int mt = 0; mt < 4; ++mt) {
        bf16x8 a = *(const bf16x8*)(sA + (mt * 16 + l16) * LDA + ks * 32 + quad * 8);
        acc[mt][0] = __builtin_amdgcn_mfma_f32_16x16x32_bf16(a, wf1[0][ks], acc[mt][0], 0, 0, 0);
        acc[mt][1] = __builtin_amdgcn_mfma_f32_16x16x32_bf16(a, wf1[1][ks], acc[mt][1], 0, 0, 0);
      }
    }

#pragma unroll
    for (int mt = 0; mt < 4; ++mt)
#pragma unroll
      for (int nt = 0; nt < 2; ++nt)
#pragma unroll
        for (int rg = 0; rg < 4; ++rg) {
          float x = silu_f(acc[mt][nt][rg] + bias1[nt]);
          sT[(mt * 16 + quad * 4 + rg) * LDT + wcol + nt * 16 + l16] = f2b(x);
        }
    __syncthreads();

    f32x4 acc2[4][2];
#pragma unroll
    for (int mt = 0; mt < 4; ++mt)
#pragma unroll
      for (int nt = 0; nt < 2; ++nt) {
        f32x4 z = {0.0f, 0.0f, 0.0f, 0.0f};
        acc2[mt][nt] = z;
      }
#pragma unroll
    for (int ks = 0; ks < 4; ++ks) {
#pragma unroll
      for (int mt = 0; mt < 4; ++mt) {
        bf16x8 a = *(const bf16x8*)(sT + (mt * 16 + l16) * LDT + ks * 32 + quad * 8);
        acc2[mt][0] = __builtin_amdgcn_mfma_f32_16x16x32_bf16(a, wf2[0][ks], acc2[mt][0], 0, 0, 0);
        acc2[mt][1] = __builtin_amdgcn_mfma_f32_16x16x32_bf16(a, wf2[1][ks], acc2[mt][1], 0, 0, 0);
      }
    }

    // ---- epilogue: residual add, bias, fp32 store (no silu on layer 2) ----
#pragma unroll
    for (int mt = 0; mt < 4; ++mt) {
#pragma unroll
      for (int rg = 0; rg < 4; ++rg) {
        const int m = mt * 16 + quad * 4 + rg;
        const int node = n0 + m;
        if (node < NQ) {
#pragma unroll
          for (int nt = 0; nt < 2; ++nt) {
            const int n = wcol + nt * 16 + l16;
            float x = acc2[mt][nt][rg] + bias2[nt] + h_q[(size_t)node * DD + n];
            out[(size_t)node * DD + n] = x;
          }
        }
      }
    }
    __syncthreads();
  }
}

extern "C" void kernel_launch(void* const* d_in, const int* in_sizes, int n_in,
                              void* d_out, int out_size, void* d_ws, size_t ws_size,
                              hipStream_t stream) {
  const float* h_q  = (const float*)d_in[0];
  const float* h_kv = (const float*)d_in[1];
  const int* eidx   = (const int*)d_in[2];
  const float* We1  = (const float*)d_in[3];
  const float* be1  = (const float*)d_in[4];
  const float* We2  = (const float*)d_in[5];
  const float* be2  = (const float*)d_in[6];
  const float* Wn1  = (const float*)d_in[7];
  const float* bn1  = (const float*)d_in[8];
  const float* Wn2  = (const float*)d_in[9];
  const float* bn2  = (const float*)d_in[10];

  float* out = (float*)d_out;            // [NQ*DD] h_q_new, then [NE*HH] mij
  float* mij = out + (size_t)NQ * DD;

  // workspace layout (each section 256B-aligned):
  //   agg | offs | cur | cnt | blksum | blkoff | eid | hqb | hkvb
  auto align_up = [](size_t x) { return (x + 255) & ~(size_t)255; };
  char* ws = (char*)d_ws;
  size_t woff = 0;
  float* agg = (float*)(ws + woff);  woff = align_up(woff + (size_t)NQ * HH * sizeof(float));
  int* offs   = (int*)(ws + woff);   woff = align_up(woff + (size_t)(NQ + 1) * sizeof(int));
  int* cur    = (int*)(ws + woff);   woff = align_up(woff + (size_t)NQ * sizeof(int));
  int* cnt    = (int*)(ws + woff);   woff = align_up(woff + (size_t)NQ * sizeof(int));
  int* blksum = (int*)(ws + woff);   woff = align_up(woff + (size_t)NCH * sizeof(int));
  int* blkoff = (int*)(ws + woff);   woff = align_up(woff + (size_t)NCH * sizeof(int));
  int* eid    = (int*)(ws + woff);   woff = align_up(woff + (size_t)NE * sizeof(int));
  const size_t need_csr = woff;
  unsigned short* hqb  = (unsigned short*)(ws + woff);
  woff = align_up(woff + (size_t)NQ * DD * sizeof(unsigned short));
  unsigned short* hkvb = (unsigned short*)(ws + woff);
  woff = align_up(woff + (size_t)NKV * DD * sizeof(unsigned short));
  const size_t need_full = woff;

  const int etiles = NE / BM;              // 10000 exactly
  const int ntiles = (NQ + BM - 1) / BM;   // 313
  const int egrid  = 768;                  // 3 blocks/CU * 256 CUs, persistent

  if (ws_size >= need_full) {
    // ---- full path: pre-converted bf16 gather + deterministic CSR agg ----
    hipMemsetAsync(cnt, 0, (size_t)NQ * sizeof(int), stream);
    conv_kernel<<<(NQ * DD / 8 + 255) / 256, 256, 0, stream>>>(h_q, hqb, NQ * DD / 8);
    conv_kernel<<<(NKV * DD / 8 + 255) / 256, 256, 0, stream>>>(h_kv, hkvb, NKV * DD / 8);
    hist_kernel<<<NE / 256, 256, 0, stream>>>(eidx, cnt);
    scan1_kernel<<<NCH, 256, 0, stream>>>(cnt, offs, blksum);
    scan2_kernel<<<1, 128, 0, stream>>>(blksum, blkoff, offs);
    scan3_kernel<<<NCH, 256, 0, stream>>>(offs, cur, blkoff);
    scatter_kernel<<<NE / 256, 256, 0, stream>>>(eidx, cur, eid);
    edge_kernel<true, false><<<egrid, 256, 0, stream>>>(
        h_q, h_kv, hqb, hkvb, eidx, eidx + NE, We1, be1, We2, be2, mij, agg, etiles);
    agg_kernel<<<(NQ * 64) / 256, 256, 0, stream>>>(mij, offs, eid, agg);
    node_kernel<<<ntiles, 256, 0, stream>>>(h_q, agg, Wn1, bn1, Wn2, bn2, out, ntiles);
  } else if (ws_size >= need_csr) {
    // ---- CSR path without preconv ----
    hipMemsetAsync(cnt, 0, (size_t)NQ * sizeof(int), stream);
    hist_kernel<<<NE / 256, 256, 0, stream>>>(eidx, cnt);
    scan1_kernel<<<NCH, 256, 0, stream>>>(cnt, offs, blksum);
    scan2_kernel<<<1, 128, 0, stream>>>(blksum, blkoff, offs);
    scan3_kernel<<<NCH, 256, 0, stream>>>(offs, cur, blkoff);
    scatter_kernel<<<NE / 256, 256, 0, stream>>>(eidx, cur, eid);
    edge_kernel<false, false><<<egrid, 256, 0, stream>>>(
        h_q, h_kv, nullptr, nullptr, eidx, eidx + NE, We1, be1, We2, be2, mij, agg, etiles);
    agg_kernel<<<(NQ * 64) / 256, 256, 0, stream>>>(mij, offs, eid, agg);
    node_kernel<<<ntiles, 256, 0, stream>>>(h_q, agg, Wn1, bn1, Wn2, bn2, out, ntiles);
  } else {
    // ---- fallback: previously-verified fp32-atomic path ----
    hipMemsetAsync(agg, 0, (size_t)NQ * HH * sizeof(float), stream);
    edge_kernel<false, true><<<egrid, 256, 0, stream>>>(
        h_q, h_kv, nullptr, nullptr, eidx, eidx + NE, We1, be1, We2, be2, mij, agg, etiles);
    node_kernel<<<ntiles, 256, 0, stream>>>(h_q, agg, Wn1, bn1, Wn2, bn2, out, ntiles);
  }
}

// Round 15
// 698.211 us; speedup vs baseline: 1.0973x; 1.0973x over previous
//
#include <hip/hip_runtime.h>
#include <hip/hip_bf16.h>

#define NQ 20000
#define NKV 20000
#define NE 640000
#define DD 128
#define HH 128

typedef short bf16x8 __attribute__((ext_vector_type(8)));
typedef float f32x4 __attribute__((ext_vector_type(4)));

static __device__ __forceinline__ unsigned short f2b(float f) {
  unsigned u = __builtin_bit_cast(unsigned, f);
  u += 0x7fffu + ((u >> 16) & 1u);  // RNE
  return (unsigned short)(u >> 16);
}
static __device__ __forceinline__ float silu_f(float x) {
  return x / (1.0f + __expf(-x));
}

constexpr int BM  = 64;   // edges (or nodes) per workgroup tile
constexpr int LDA = 264;  // 256 + 8 pad (bf16 elems)
constexpr int LDT = 136;  // 128 + 8 pad
constexpr int NCH = (NQ + 255) / 256;  // 79 scan chunks

// Convert 8 consecutive floats -> 8 bf16 packed in a uint4
static __device__ __forceinline__ uint4 pack8(const float4* s4) {
  float4 a = s4[0], b = s4[1];
  union { unsigned short u[8]; uint4 q; } p;
  p.u[0] = f2b(a.x); p.u[1] = f2b(a.y); p.u[2] = f2b(a.z); p.u[3] = f2b(a.w);
  p.u[4] = f2b(b.x); p.u[5] = f2b(b.y); p.u[6] = f2b(b.z); p.u[7] = f2b(b.w);
  return p.q;
}

// ============ one-time fp32 -> bf16 conversion of node features ============
__global__ __launch_bounds__(256) void conv_kernel(const float* __restrict__ src,
                                                   unsigned short* __restrict__ dst,
                                                   int n8) {
  const int i = blockIdx.x * 256 + threadIdx.x;
  if (i < n8) ((uint4*)dst)[i] = pack8(((const float4*)src) + 2 * i);
}

// ==== pre-pack We2 into MFMA fragment order: chunk c=(((wave*2+nt)*4+ks)*4
//      +quad)*16+l16 holds the 8 bf16 elems j of B[k=ks*32+quad*8+j][n] ====
__global__ __launch_bounds__(256) void packw2_kernel(const float* __restrict__ We2,
                                                     unsigned short* __restrict__ We2p) {
  const int c = blockIdx.x * 256 + threadIdx.x;  // 2048 chunks * 16B = 32KB
  if (c >= 2048) return;
  const int l16 = c & 15;
  int t = c >> 4;
  const int quad = t & 3; t >>= 2;
  const int ks = t & 3;   t >>= 2;
  const int nt = t & 1;   t >>= 1;
  const int wave = t;  // 0..3
  const int n = wave * 32 + nt * 16 + l16;
  union { unsigned short u[8]; uint4 q; } p;
#pragma unroll
  for (int j = 0; j < 8; ++j)
    p.u[j] = f2b(We2[(size_t)(ks * 32 + quad * 8 + j) * HH + n]);
  ((uint4*)We2p)[c] = p.q;
}

// ================= CSR build: histogram -> scan -> scatter =================
__global__ __launch_bounds__(256) void hist_kernel(const int* __restrict__ erow,
                                                   int* __restrict__ cnt) {
  const int i = blockIdx.x * 256 + threadIdx.x;
  if (i < NE) atomicAdd(&cnt[erow[i]], 1);
}

// Hierarchical exclusive scan over NQ counts (3 parallel phases).
__global__ __launch_bounds__(256) void scan1_kernel(const int* __restrict__ cnt,
                                                    int* __restrict__ offs,
                                                    int* __restrict__ blksum) {
  __shared__ int s[256];
  const int tid = threadIdx.x;
  const int idx = blockIdx.x * 256 + tid;
  const int v = (idx < NQ) ? cnt[idx] : 0;
  s[tid] = v;
  __syncthreads();
#pragma unroll
  for (int off = 1; off < 256; off <<= 1) {
    const int t = (tid >= off) ? s[tid - off] : 0;
    __syncthreads();
    s[tid] += t;
    __syncthreads();
  }
  if (idx < NQ) offs[idx] = s[tid] - v;  // exclusive within chunk
  if (tid == 255) blksum[blockIdx.x] = s[255];
}

__global__ __launch_bounds__(128) void scan2_kernel(const int* __restrict__ blksum,
                                                    int* __restrict__ blkoff,
                                                    int* __restrict__ offs) {
  __shared__ int s[128];
  const int tid = threadIdx.x;
  const int v = (tid < NCH) ? blksum[tid] : 0;
  s[tid] = v;
  __syncthreads();
#pragma unroll
  for (int off = 1; off < 128; off <<= 1) {
    const int t = (tid >= off) ? s[tid - off] : 0;
    __syncthreads();
    s[tid] += t;
    __syncthreads();
  }
  if (tid < NCH) blkoff[tid] = s[tid] - v;
  if (tid == 127) offs[NQ] = s[127];  // grand total (entries >= NCH are 0)
}

__global__ __launch_bounds__(256) void scan3_kernel(int* __restrict__ offs,
                                                    int* __restrict__ cur,
                                                    const int* __restrict__ blkoff) {
  const int idx = blockIdx.x * 256 + threadIdx.x;
  if (idx < NQ) {
    const int o = offs[idx] + blkoff[blockIdx.x];
    offs[idx] = o;
    cur[idx] = o;
  }
}

__global__ __launch_bounds__(256) void scatter_kernel(const int* __restrict__ erow,
                                                      int* __restrict__ cur,
                                                      int* __restrict__ eid) {
  const int i = blockIdx.x * 256 + threadIdx.x;
  if (i < NE) {
    const int p = atomicAdd(&cur[erow[i]], 1);
    eid[p] = i;
  }
}

// ============ deterministic aggregation: one wave per query row ============
// 4-way unroll: 4 independent 512B row gathers in flight per wave.
__global__ __launch_bounds__(256) void agg_kernel(const float* __restrict__ mij,
                                                  const int* __restrict__ offs,
                                                  const int* __restrict__ eid,
                                                  float* __restrict__ agg) {
  const int w = (blockIdx.x * 256 + threadIdx.x) >> 6;  // wave id = row
  const int lane = threadIdx.x & 63;
  if (w >= NQ) return;
  const int s = offs[w];
  const int e = offs[w + 1];
  float2 a0 = {0.0f, 0.0f};
  float2 a1 = {0.0f, 0.0f};
  float2 a2 = {0.0f, 0.0f};
  float2 a3 = {0.0f, 0.0f};
  int i = s;
  for (; i + 4 <= e; i += 4) {
    const int e0 = eid[i];
    const int e1 = eid[i + 1];
    const int e2 = eid[i + 2];
    const int e3 = eid[i + 3];
    const float2 v0 = ((const float2*)(mij + (size_t)e0 * HH))[lane];
    const float2 v1 = ((const float2*)(mij + (size_t)e1 * HH))[lane];
    const float2 v2 = ((const float2*)(mij + (size_t)e2 * HH))[lane];
    const float2 v3 = ((const float2*)(mij + (size_t)e3 * HH))[lane];
    a0.x += v0.x; a0.y += v0.y;
    a1.x += v1.x; a1.y += v1.y;
    a2.x += v2.x; a2.y += v2.y;
    a3.x += v3.x; a3.y += v3.y;
  }
  for (; i < e; ++i) {
    const int e0 = eid[i];
    const float2 v0 = ((const float2*)(mij + (size_t)e0 * HH))[lane];
    a0.x += v0.x; a0.y += v0.y;
  }
  a0.x += a1.x; a0.y += a1.y;
  a2.x += a3.x; a2.y += a3.y;
  a0.x += a2.x; a0.y += a2.y;
  ((float2*)(agg + (size_t)w * HH))[lane] = a0;
}

// ---------------- edge kernel: mij = silu(silu([hq|hkv]@We1+be1)@We2+be2)
//   PRECONV=true (full path): bf16 gather, sT aliases sA, and wf2 STREAMED
//     from L2-resident pre-packed We2p in two 16-reg half-chunks during
//     layer 2. Peak live set ~ wf1(64)+acc(32)+chunk(16)+misc(~12) = ~124
//     <= 128 -> launch_bounds(256,4), 4 blocks/CU (was reg-capped at 3).
//   PRECONV=false (fallback tiers): old persistent-wf2 code at (256,3).
//   r8 lesson: (256,4) with ~156 regs SPILLS (WRITE_SIZE 320->702MB).
template <bool PRECONV, bool DO_ATOMIC>
__global__ __launch_bounds__(256, PRECONV ? 4 : 3) void edge_kernel(
    const float* __restrict__ h_q,
    const float* __restrict__ h_kv,
    const unsigned short* __restrict__ hqb,
    const unsigned short* __restrict__ hkvb,
    const unsigned short* __restrict__ We2p,
    const int* __restrict__ erow,
    const int* __restrict__ ecol,
    const float* __restrict__ We1,
    const float* __restrict__ be1,
    const float* __restrict__ We2,
    const float* __restrict__ be2,
    float* __restrict__ mij,
    float* __restrict__ agg,
    int num_tiles) {
  __shared__ __align__(16) unsigned short sA[BM * LDA];
  __shared__ int sRow[BM];
  unsigned short* sT = sA;  // aliased activation buffer (layer1 drains sA first)

  const int tid  = threadIdx.x;
  const int wave = tid >> 6;
  const int lane = tid & 63;
  const int quad = lane >> 4;
  const int l16  = lane & 15;
  const int wcol = wave * 32;  // this wave's 32-column strip

  // ---- persistent weight B-fragments: B[k][n], n=l16, k=quad*8+j ----
  bf16x8 wf1[2][8];
  bf16x8 wf2[2][4];  // only initialized/used when !PRECONV (DCE'd otherwise)
  float bias1[2], bias2[2];
#pragma unroll
  for (int nt = 0; nt < 2; ++nt) {
    const int n = wcol + nt * 16 + l16;
    bias1[nt] = be1[n];
    bias2[nt] = be2[n];
#pragma unroll
    for (int ks = 0; ks < 8; ++ks) {
      const int kb = ks * 32 + quad * 8;
      bf16x8 v;
#pragma unroll
      for (int j = 0; j < 8; ++j) v[j] = (short)f2b(We1[(kb + j) * HH + n]);
      wf1[nt][ks] = v;
    }
    if (!PRECONV) {
#pragma unroll
      for (int ks = 0; ks < 4; ++ks) {
        const int kb = ks * 32 + quad * 8;
        bf16x8 v;
#pragma unroll
        for (int j = 0; j < 8; ++j) v[j] = (short)f2b(We2[(kb + j) * HH + n]);
        wf2[nt][ks] = v;
      }
    }
  }

  for (int tile = blockIdx.x; tile < num_tiles; tile += gridDim.x) {
    const int e0 = tile * BM;

    // ---- stage: 4 threads per edge ----
    {
      const int el = tid >> 2;
      const int part = tid & 3;
      const int e = e0 + el;
      const int r = erow[e];
      const int c = ecol[e];
      if (part == 0) sRow[el] = r;
      uint4* d4 = (uint4*)(sA + el * LDA + part * 64);
      if (PRECONV) {
        // pure copy: 64 bf16 = 8x uint4, no conversion VALU
        const unsigned short* src =
            (part < 2 ? hqb + (size_t)r * DD : hkvb + (size_t)c * DD) + (part & 1) * 64;
        const uint4* s4 = (const uint4*)src;
#pragma unroll
        for (int i = 0; i < 8; ++i) d4[i] = s4[i];
      } else {
        const float* src =
            (part < 2 ? h_q + (size_t)r * DD : h_kv + (size_t)c * DD) + (part & 1) * 64;
        const float4* s4 = (const float4*)src;
#pragma unroll
        for (int i = 0; i < 8; ++i) d4[i] = pack8(s4 + 2 * i);
      }
    }
    __syncthreads();

    // ---- layer 1: [64x256] @ We1 (drains sA into accumulators) ----
    f32x4 acc[4][2];
#pragma unroll
    for (int mt = 0; mt < 4; ++mt)
#pragma unroll
      for (int nt = 0; nt < 2; ++nt) {
        f32x4 z = {0.0f, 0.0f, 0.0f, 0.0f};
        acc[mt][nt] = z;
      }
#pragma unroll
    for (int ks = 0; ks < 8; ++ks) {
#pragma unroll
      for (int mt = 0; mt < 4; ++mt) {
        bf16x8 a = *(const bf16x8*)(sA + (mt * 16 + l16) * LDA + ks * 32 + quad * 8);
        acc[mt][0] = __builtin_amdgcn_mfma_f32_16x16x32_bf16(a, wf1[0][ks], acc[mt][0], 0, 0, 0);
        acc[mt][1] = __builtin_amdgcn_mfma_f32_16x16x32_bf16(a, wf1[1][ks], acc[mt][1], 0, 0, 0);
      }
    }
    __syncthreads();  // all waves done READING sA before aliased overwrite

    // ---- silu -> sT (=sA aliased; C-layout: col=l16, row=quad*4+rg) ----
#pragma unroll
    for (int mt = 0; mt < 4; ++mt)
#pragma unroll
      for (int nt = 0; nt < 2; ++nt)
#pragma unroll
        for (int rg = 0; rg < 4; ++rg) {
          float x = silu_f(acc[mt][nt][rg] + bias1[nt]);
          sT[(mt * 16 + quad * 4 + rg) * LDT + wcol + nt * 16 + l16] = f2b(x);
        }
    __syncthreads();

    // ---- layer 2: [64x128] @ We2 ----
    f32x4 acc2[4][2];
#pragma unroll
    for (int mt = 0; mt < 4; ++mt)
#pragma unroll
      for (int nt = 0; nt < 2; ++nt) {
        f32x4 z = {0.0f, 0.0f, 0.0f, 0.0f};
        acc2[mt][nt] = z;
      }
    if (PRECONV) {
      // stream wf2 from L2 prepack in 2 half-chunks (16 regs live each)
#pragma unroll
      for (int half = 0; half < 2; ++half) {
        bf16x8 w00, w01, w10, w11;  // [nt][kk]
        w00 = *(const bf16x8*)(We2p + ((((size_t)(wave * 2 + 0) * 4 + half * 2 + 0) * 4 + quad) * 16 + l16) * 8);
        w01 = *(const bf16x8*)(We2p + ((((size_t)(wave * 2 + 0) * 4 + half * 2 + 1) * 4 + quad) * 16 + l16) * 8);
        w10 = *(const bf16x8*)(We2p + ((((size_t)(wave * 2 + 1) * 4 + half * 2 + 0) * 4 + quad) * 16 + l16) * 8);
        w11 = *(const bf16x8*)(We2p + ((((size_t)(wave * 2 + 1) * 4 + half * 2 + 1) * 4 + quad) * 16 + l16) * 8);
#pragma unroll
        for (int kk = 0; kk < 2; ++kk) {
          const int ks = half * 2 + kk;
#pragma unroll
          for (int mt = 0; mt < 4; ++mt) {
            bf16x8 a = *(const bf16x8*)(sT + (mt * 16 + l16) * LDT + ks * 32 + quad * 8);
            acc2[mt][0] = __builtin_amdgcn_mfma_f32_16x16x32_bf16(a, kk ? w01 : w00, acc2[mt][0], 0, 0, 0);
            acc2[mt][1] = __builtin_amdgcn_mfma_f32_16x16x32_bf16(a, kk ? w11 : w10, acc2[mt][1], 0, 0, 0);
          }
        }
      }
    } else {
#pragma unroll
      for (int ks = 0; ks < 4; ++ks) {
#pragma unroll
        for (int mt = 0; mt < 4; ++mt) {
          bf16x8 a = *(const bf16x8*)(sT + (mt * 16 + l16) * LDT + ks * 32 + quad * 8);
          acc2[mt][0] = __builtin_amdgcn_mfma_f32_16x16x32_bf16(a, wf2[0][ks], acc2[mt][0], 0, 0, 0);
          acc2[mt][1] = __builtin_amdgcn_mfma_f32_16x16x32_bf16(a, wf2[1][ks], acc2[mt][1], 0, 0, 0);
        }
      }
    }

    // ---- epilogue: mij store (fp32); atomic scatter only in fallback ----
#pragma unroll
    for (int mt = 0; mt < 4; ++mt) {
#pragma unroll
      for (int rg = 0; rg < 4; ++rg) {
        const int m = mt * 16 + quad * 4 + rg;
        const size_t e = (size_t)(e0 + m);
        const int gr = sRow[m];
#pragma unroll
        for (int nt = 0; nt < 2; ++nt) {
          const int n = wcol + nt * 16 + l16;
          float x = silu_f(acc2[mt][nt][rg] + bias2[nt]);
          mij[e * HH + n] = x;
          if (DO_ATOMIC) atomicAdd(&agg[(size_t)gr * HH + n], x);
        }
      }
    }
    __syncthreads();  // protect sA/sT/sRow against next iteration's staging
  }
}

// ---------------- node kernel: out = h_q + silu([h_q|agg]@Wn1+bn1)@Wn2+bn2 ----
__global__ __launch_bounds__(256, 2) void node_kernel(
    const float* __restrict__ h_q,
    const float* __restrict__ agg,
    const float* __restrict__ Wn1,
    const float* __restrict__ bn1,
    const float* __restrict__ Wn2,
    const float* __restrict__ bn2,
    float* __restrict__ out,
    int num_tiles) {
  __shared__ __align__(16) unsigned short sA[BM * LDA];
  __shared__ __align__(16) unsigned short sT[BM * LDT];

  const int tid  = threadIdx.x;
  const int wave = tid >> 6;
  const int lane = tid & 63;
  const int quad = lane >> 4;
  const int l16  = lane & 15;
  const int wcol = wave * 32;

  bf16x8 wf1[2][8];
  bf16x8 wf2[2][4];
  float bias1[2], bias2[2];
#pragma unroll
  for (int nt = 0; nt < 2; ++nt) {
    const int n = wcol + nt * 16 + l16;
    bias1[nt] = bn1[n];
    bias2[nt] = bn2[n];
#pragma unroll
    for (int ks = 0; ks < 8; ++ks) {
      const int kb = ks * 32 + quad * 8;
      bf16x8 v;
#pragma unroll
      for (int j = 0; j < 8; ++j) v[j] = (short)f2b(Wn1[(kb + j) * HH + n]);
      wf1[nt][ks] = v;
    }
#pragma unroll
    for (int ks = 0; ks < 4; ++ks) {
      const int kb = ks * 32 + quad * 8;
      bf16x8 v;
#pragma unroll
      for (int j = 0; j < 8; ++j) v[j] = (short)f2b(Wn2[(kb + j) * HH + n]);
      wf2[nt][ks] = v;
    }
  }

  for (int tile = blockIdx.x; tile < num_tiles; tile += gridDim.x) {
    const int n0 = tile * BM;

    // ---- stage: parts 0/1 = h_q, parts 2/3 = agg (both fp32 -> bf16) ----
    {
      const int el = tid >> 2;
      const int part = tid & 3;
      const int node = n0 + el;
      uint4* d4 = (uint4*)(sA + el * LDA + part * 64);
      if (node < NQ) {
        const float* src =
            (part < 2 ? h_q + (size_t)node * DD : agg + (size_t)node * HH) + (part & 1) * 64;
        const float4* s4 = (const float4*)src;
#pragma unroll
        for (int i = 0; i < 8; ++i) d4[i] = pack8(s4 + 2 * i);
      } else {
        uint4 z = {0u, 0u, 0u, 0u};
#pragma unroll
        for (int i = 0; i < 8; ++i) d4[i] = z;
      }
    }
    __syncthreads();

    f32x4 acc[4][2];
#pragma unroll
    for (int mt = 0; mt < 4; ++mt)
#pragma unroll
      for (int nt = 0; nt < 2; ++nt) {
        f32x4 z = {0.0f, 0.0f, 0.0f, 0.0f};
        acc[mt][nt] = z;
      }
#pragma unroll
    for (int ks = 0; ks < 8; ++ks) {
#pragma unroll
      for (int mt = 0; mt < 4; ++mt) {
        bf16x8 a = *(const bf16x8*)(sA + (mt * 16 + l16) * LDA + ks * 32 + quad * 8);
        acc[mt][0] = __builtin_amdgcn_mfma_f32_16x16x32_bf16(a, wf1[0][ks], acc[mt][0], 0, 0, 0);
        acc[mt][1] = __builtin_amdgcn_mfma_f32_16x16x32_bf16(a, wf1[1][ks], acc[mt][1], 0, 0, 0);
      }
    }

#pragma unroll
    for (int mt = 0; mt < 4; ++mt)
#pragma unroll
      for (int nt = 0; nt < 2; ++nt)
#pragma unroll
        for (int rg = 0; rg < 4; ++rg) {
          float x = silu_f(acc[mt][nt][rg] + bias1[nt]);
          sT[(mt * 16 + quad * 4 + rg) * LDT + wcol + nt * 16 + l16] = f2b(x);
        }
    __syncthreads();

    f32x4 acc2[4][2];
#pragma unroll
    for (int mt = 0; mt < 4; ++mt)
#pragma unroll
      for (int nt = 0; nt < 2; ++nt) {
        f32x4 z = {0.0f, 0.0f, 0.0f, 0.0f};
        acc2[mt][nt] = z;
      }
#pragma unroll
    for (int ks = 0; ks < 4; ++ks) {
#pragma unroll
      for (int mt = 0; mt < 4; ++mt) {
        bf16x8 a = *(const bf16x8*)(sT + (mt * 16 + l16) * LDT + ks * 32 + quad * 8);
        acc2[mt][0] = __builtin_amdgcn_mfma_f32_16x16x32_bf16(a, wf2[0][ks], acc2[mt][0], 0, 0, 0);
        acc2[mt][1] = __builtin_amdgcn_mfma_f32_16x16x32_bf16(a, wf2[1][ks], acc2[mt][1], 0, 0, 0);
      }
    }

    // ---- epilogue: residual add, bias, fp32 store (no silu on layer 2) ----
#pragma unroll
    for (int mt = 0; mt < 4; ++mt) {
#pragma unroll
      for (int rg = 0; rg < 4; ++rg) {
        const int m = mt * 16 + quad * 4 + rg;
        const int node = n0 + m;
        if (node < NQ) {
#pragma unroll
          for (int nt = 0; nt < 2; ++nt) {
            const int n = wcol + nt * 16 + l16;
            float x = acc2[mt][nt][rg] + bias2[nt] + h_q[(size_t)node * DD + n];
            out[(size_t)node * DD + n] = x;
          }
        }
      }
    }
    __syncthreads();
  }
}

extern "C" void kernel_launch(void* const* d_in, const int* in_sizes, int n_in,
                              void* d_out, int out_size, void* d_ws, size_t ws_size,
                              hipStream_t stream) {
  const float* h_q  = (const float*)d_in[0];
  const float* h_kv = (const float*)d_in[1];
  const int* eidx   = (const int*)d_in[2];
  const float* We1  = (const float*)d_in[3];
  const float* be1  = (const float*)d_in[4];
  const float* We2  = (const float*)d_in[5];
  const float* be2  = (const float*)d_in[6];
  const float* Wn1  = (const float*)d_in[7];
  const float* bn1  = (const float*)d_in[8];
  const float* Wn2  = (const float*)d_in[9];
  const float* bn2  = (const float*)d_in[10];

  float* out = (float*)d_out;            // [NQ*DD] h_q_new, then [NE*HH] mij
  float* mij = out + (size_t)NQ * DD;

  // workspace layout (each section 256B-aligned):
  //   agg | offs | cur | cnt | blksum | blkoff | eid | hqb | hkvb | We2p
  auto align_up = [](size_t x) { return (x + 255) & ~(size_t)255; };
  char* ws = (char*)d_ws;
  size_t woff = 0;
  float* agg = (float*)(ws + woff);  woff = align_up(woff + (size_t)NQ * HH * sizeof(float));
  int* offs   = (int*)(ws + woff);   woff = align_up(woff + (size_t)(NQ + 1) * sizeof(int));
  int* cur    = (int*)(ws + woff);   woff = align_up(woff + (size_t)NQ * sizeof(int));
  int* cnt    = (int*)(ws + woff);   woff = align_up(woff + (size_t)NQ * sizeof(int));
  int* blksum = (int*)(ws + woff);   woff = align_up(woff + (size_t)NCH * sizeof(int));
  int* blkoff = (int*)(ws + woff);   woff = align_up(woff + (size_t)NCH * sizeof(int));
  int* eid    = (int*)(ws + woff);   woff = align_up(woff + (size_t)NE * sizeof(int));
  const size_t need_csr = woff;
  unsigned short* hqb  = (unsigned short*)(ws + woff);
  woff = align_up(woff + (size_t)NQ * DD * sizeof(unsigned short));
  unsigned short* hkvb = (unsigned short*)(ws + woff);
  woff = align_up(woff + (size_t)NKV * DD * sizeof(unsigned short));
  unsigned short* We2p = (unsigned short*)(ws + woff);
  woff = align_up(woff + (size_t)2048 * 16);  // 32KB packed We2
  const size_t need_full = woff;

  const int etiles = NE / BM;              // 10000 exactly
  const int ntiles = (NQ + BM - 1) / BM;   // 313

  if (ws_size >= need_full) {
    // ---- full path: bf16 gather + streamed wf2 + deterministic CSR agg ----
    hipMemsetAsync(cnt, 0, (size_t)NQ * sizeof(int), stream);
    conv_kernel<<<(NQ * DD / 8 + 255) / 256, 256, 0, stream>>>(h_q, hqb, NQ * DD / 8);
    conv_kernel<<<(NKV * DD / 8 + 255) / 256, 256, 0, stream>>>(h_kv, hkvb, NKV * DD / 8);
    packw2_kernel<<<8, 256, 0, stream>>>(We2, We2p);
    hist_kernel<<<NE / 256, 256, 0, stream>>>(eidx, cnt);
    scan1_kernel<<<NCH, 256, 0, stream>>>(cnt, offs, blksum);
    scan2_kernel<<<1, 128, 0, stream>>>(blksum, blkoff, offs);
    scan3_kernel<<<NCH, 256, 0, stream>>>(offs, cur, blkoff);
    scatter_kernel<<<NE / 256, 256, 0, stream>>>(eidx, cur, eid);
    edge_kernel<true, false><<<1024, 256, 0, stream>>>(
        h_q, h_kv, hqb, hkvb, We2p, eidx, eidx + NE, We1, be1, We2, be2, mij, agg, etiles);
    agg_kernel<<<(NQ * 64) / 256, 256, 0, stream>>>(mij, offs, eid, agg);
    node_kernel<<<ntiles, 256, 0, stream>>>(h_q, agg, Wn1, bn1, Wn2, bn2, out, ntiles);
  } else if (ws_size >= need_csr) {
    // ---- CSR path without preconv (persistent wf2, (256,3)) ----
    hipMemsetAsync(cnt, 0, (size_t)NQ * sizeof(int), stream);
    hist_kernel<<<NE / 256, 256, 0, stream>>>(eidx, cnt);
    scan1_kernel<<<NCH, 256, 0, stream>>>(cnt, offs, blksum);
    scan2_kernel<<<1, 128, 0, stream>>>(blksum, blkoff, offs);
    scan3_kernel<<<NCH, 256, 0, stream>>>(offs, cur, blkoff);
    scatter_kernel<<<NE / 256, 256, 0, stream>>>(eidx, cur, eid);
    edge_kernel<false, false><<<768, 256, 0, stream>>>(
        h_q, h_kv, nullptr, nullptr, nullptr, eidx, eidx + NE, We1, be1, We2, be2, mij, agg, etiles);
    agg_kernel<<<(NQ * 64) / 256, 256, 0, stream>>>(mij, offs, eid, agg);
    node_kernel<<<ntiles, 256, 0, stream>>>(h_q, agg, Wn1, bn1, Wn2, bn2, out, ntiles);
  } else {
    // ---- fallback: previously-verified fp32-atomic path ----
    hipMemsetAsync(agg, 0, (size_t)NQ * HH * sizeof(float), stream);
    edge_kernel<false, true><<<768, 256, 0, stream>>>(
        h_q, h_kv, nullptr, nullptr, nullptr, eidx, eidx + NE, We1, be1, We2, be2, mij, agg, etiles);
    node_kernel<<<ntiles, 256, 0, stream>>>(h_q, agg, Wn1, bn1, Wn2, bn2, out, ntiles);
  }
}

// Round 16
// 666.487 us; speedup vs baseline: 1.1496x; 1.0476x over previous
//
#include <hip/hip_runtime.h>
#include <hip/hip_bf16.h>

#define NQ 20000
#define NKV 20000
#define NE 640000
#define DD 128
#define HH 128

typedef short bf16x8 __attribute__((ext_vector_type(8)));
typedef float f32x4 __attribute__((ext_vector_type(4)));

static __device__ __forceinline__ unsigned short f2b(float f) {
  unsigned u = __builtin_bit_cast(unsigned, f);
  u += 0x7fffu + ((u >> 16) & 1u);  // RNE
  return (unsigned short)(u >> 16);
}
static __device__ __forceinline__ float silu_f(float x) {
  return x / (1.0f + __expf(-x));
}

constexpr int BM  = 64;   // edges (or nodes) per workgroup tile
constexpr int LDA = 264;  // 256 + 8 pad (bf16 elems)
constexpr int LDT = 136;  // 128 + 8 pad
constexpr int NCH = (NQ + 255) / 256;  // 79 scan chunks

// Convert 8 consecutive floats -> 8 bf16 packed in a uint4
static __device__ __forceinline__ uint4 pack8(const float4* s4) {
  float4 a = s4[0], b = s4[1];
  union { unsigned short u[8]; uint4 q; } p;
  p.u[0] = f2b(a.x); p.u[1] = f2b(a.y); p.u[2] = f2b(a.z); p.u[3] = f2b(a.w);
  p.u[4] = f2b(b.x); p.u[5] = f2b(b.y); p.u[6] = f2b(b.z); p.u[7] = f2b(b.w);
  return p.q;
}

// ============ one-time fp32 -> bf16 conversion of node features ============
__global__ __launch_bounds__(256) void conv_kernel(const float* __restrict__ src,
                                                   unsigned short* __restrict__ dst,
                                                   int n8) {
  const int i = blockIdx.x * 256 + threadIdx.x;
  if (i < n8) ((uint4*)dst)[i] = pack8(((const float4*)src) + 2 * i);
}

// ================= CSR build: histogram -> scan -> scatter =================
__global__ __launch_bounds__(256) void hist_kernel(const int* __restrict__ erow,
                                                   int* __restrict__ cnt) {
  const int i = blockIdx.x * 256 + threadIdx.x;
  if (i < NE) atomicAdd(&cnt[erow[i]], 1);
}

// Hierarchical exclusive scan over NQ counts (3 parallel phases).
__global__ __launch_bounds__(256) void scan1_kernel(const int* __restrict__ cnt,
                                                    int* __restrict__ offs,
                                                    int* __restrict__ blksum) {
  __shared__ int s[256];
  const int tid = threadIdx.x;
  const int idx = blockIdx.x * 256 + tid;
  const int v = (idx < NQ) ? cnt[idx] : 0;
  s[tid] = v;
  __syncthreads();
#pragma unroll
  for (int off = 1; off < 256; off <<= 1) {
    const int t = (tid >= off) ? s[tid - off] : 0;
    __syncthreads();
    s[tid] += t;
    __syncthreads();
  }
  if (idx < NQ) offs[idx] = s[tid] - v;  // exclusive within chunk
  if (tid == 255) blksum[blockIdx.x] = s[255];
}

__global__ __launch_bounds__(128) void scan2_kernel(const int* __restrict__ blksum,
                                                    int* __restrict__ blkoff,
                                                    int* __restrict__ offs) {
  __shared__ int s[128];
  const int tid = threadIdx.x;
  const int v = (tid < NCH) ? blksum[tid] : 0;
  s[tid] = v;
  __syncthreads();
#pragma unroll
  for (int off = 1; off < 128; off <<= 1) {
    const int t = (tid >= off) ? s[tid - off] : 0;
    __syncthreads();
    s[tid] += t;
    __syncthreads();
  }
  if (tid < NCH) blkoff[tid] = s[tid] - v;
  if (tid == 127) offs[NQ] = s[127];  // grand total (entries >= NCH are 0)
}

__global__ __launch_bounds__(256) void scan3_kernel(int* __restrict__ offs,
                                                    int* __restrict__ cur,
                                                    const int* __restrict__ blkoff) {
  const int idx = blockIdx.x * 256 + threadIdx.x;
  if (idx < NQ) {
    const int o = offs[idx] + blkoff[blockIdx.x];
    offs[idx] = o;
    cur[idx] = o;
  }
}

__global__ __launch_bounds__(256) void scatter_kernel(const int* __restrict__ erow,
                                                      int* __restrict__ cur,
                                                      int* __restrict__ eid) {
  const int i = blockIdx.x * 256 + threadIdx.x;
  if (i < NE) {
    const int p = atomicAdd(&cur[erow[i]], 1);
    eid[p] = i;
  }
}

// ============ deterministic aggregation: one wave per query row ============
// 8-way unroll: 8 independent 512B row gathers in flight per wave (agg is
// the largest non-edge cost; roofline ~55us for 327MB re-read).
__global__ __launch_bounds__(256) void agg_kernel(const float* __restrict__ mij,
                                                  const int* __restrict__ offs,
                                                  const int* __restrict__ eid,
                                                  float* __restrict__ agg) {
  const int w = (blockIdx.x * 256 + threadIdx.x) >> 6;  // wave id = row
  const int lane = threadIdx.x & 63;
  if (w >= NQ) return;
  const int s = offs[w];
  const int e = offs[w + 1];
  float2 a0 = {0.0f, 0.0f}, a1 = {0.0f, 0.0f};
  float2 a2 = {0.0f, 0.0f}, a3 = {0.0f, 0.0f};
  float2 a4 = {0.0f, 0.0f}, a5 = {0.0f, 0.0f};
  float2 a6 = {0.0f, 0.0f}, a7 = {0.0f, 0.0f};
  int i = s;
  for (; i + 8 <= e; i += 8) {
    const int e0 = eid[i],     e1 = eid[i + 1];
    const int e2 = eid[i + 2], e3 = eid[i + 3];
    const int e4 = eid[i + 4], e5 = eid[i + 5];
    const int e6 = eid[i + 6], e7 = eid[i + 7];
    const float2 v0 = ((const float2*)(mij + (size_t)e0 * HH))[lane];
    const float2 v1 = ((const float2*)(mij + (size_t)e1 * HH))[lane];
    const float2 v2 = ((const float2*)(mij + (size_t)e2 * HH))[lane];
    const float2 v3 = ((const float2*)(mij + (size_t)e3 * HH))[lane];
    const float2 v4 = ((const float2*)(mij + (size_t)e4 * HH))[lane];
    const float2 v5 = ((const float2*)(mij + (size_t)e5 * HH))[lane];
    const float2 v6 = ((const float2*)(mij + (size_t)e6 * HH))[lane];
    const float2 v7 = ((const float2*)(mij + (size_t)e7 * HH))[lane];
    a0.x += v0.x; a0.y += v0.y;
    a1.x += v1.x; a1.y += v1.y;
    a2.x += v2.x; a2.y += v2.y;
    a3.x += v3.x; a3.y += v3.y;
    a4.x += v4.x; a4.y += v4.y;
    a5.x += v5.x; a5.y += v5.y;
    a6.x += v6.x; a6.y += v6.y;
    a7.x += v7.x; a7.y += v7.y;
  }
  for (; i < e; ++i) {
    const int e0 = eid[i];
    const float2 v0 = ((const float2*)(mij + (size_t)e0 * HH))[lane];
    a0.x += v0.x; a0.y += v0.y;
  }
  a0.x += a1.x; a0.y += a1.y;
  a2.x += a3.x; a2.y += a3.y;
  a4.x += a5.x; a4.y += a5.y;
  a6.x += a7.x; a6.y += a7.y;
  a0.x += a2.x; a0.y += a2.y;
  a4.x += a6.x; a4.y += a6.y;
  a0.x += a4.x; a0.y += a4.y;
  ((float2*)(agg + (size_t)w * HH))[lane] = a0;
}

// ---------------- edge kernel: mij = silu(silu([hq|hkv]@We1+be1)@We2+be2)
//   r7-VERIFIED config: persistent wf1+wf2 in registers, separate sT,
//   launch_bounds(256,3), grid 768. MEASURED HISTORY:
//     r6: (256,2) -> 257us, Occ 19%.   r7: (256,3) -> ~190us, Occ 30%.
//     r8: +reg prefetch -> SPILL (WRITE 320->702MB), 290us. REVERTED.
//     r15: wf2 streamed from L2 + (256,4) -> Occ 40% but FETCH +190MB
//          (We2p re-reads fall out of L2), edge 220us. REVERTED.
//   Conclusion: 3 blocks/CU with all weights persistent is the optimum of
//   the measured configs; edge's residual stall is the per-tile serial
//   chain, not occupancy.
template <bool PRECONV, bool DO_ATOMIC>
__global__ __launch_bounds__(256, 3) void edge_kernel(
    const float* __restrict__ h_q,
    const float* __restrict__ h_kv,
    const unsigned short* __restrict__ hqb,
    const unsigned short* __restrict__ hkvb,
    const int* __restrict__ erow,
    const int* __restrict__ ecol,
    const float* __restrict__ We1,
    const float* __restrict__ be1,
    const float* __restrict__ We2,
    const float* __restrict__ be2,
    float* __restrict__ mij,
    float* __restrict__ agg,
    int num_tiles) {
  __shared__ __align__(16) unsigned short sA[BM * LDA];
  __shared__ __align__(16) unsigned short sT[BM * LDT];
  __shared__ int sRow[BM];

  const int tid  = threadIdx.x;
  const int wave = tid >> 6;
  const int lane = tid & 63;
  const int quad = lane >> 4;
  const int l16  = lane & 15;
  const int wcol = wave * 32;  // this wave's 32-column strip

  // ---- persistent weight B-fragments: B[k][n], n=l16, k=quad*8+j ----
  bf16x8 wf1[2][8];
  bf16x8 wf2[2][4];
  float bias1[2], bias2[2];
#pragma unroll
  for (int nt = 0; nt < 2; ++nt) {
    const int n = wcol + nt * 16 + l16;
    bias1[nt] = be1[n];
    bias2[nt] = be2[n];
#pragma unroll
    for (int ks = 0; ks < 8; ++ks) {
      const int kb = ks * 32 + quad * 8;
      bf16x8 v;
#pragma unroll
      for (int j = 0; j < 8; ++j) v[j] = (short)f2b(We1[(kb + j) * HH + n]);
      wf1[nt][ks] = v;
    }
#pragma unroll
    for (int ks = 0; ks < 4; ++ks) {
      const int kb = ks * 32 + quad * 8;
      bf16x8 v;
#pragma unroll
      for (int j = 0; j < 8; ++j) v[j] = (short)f2b(We2[(kb + j) * HH + n]);
      wf2[nt][ks] = v;
    }
  }

  for (int tile = blockIdx.x; tile < num_tiles; tile += gridDim.x) {
    const int e0 = tile * BM;

    // ---- stage: 4 threads per edge ----
    {
      const int el = tid >> 2;
      const int part = tid & 3;
      const int e = e0 + el;
      const int r = erow[e];
      const int c = ecol[e];
      if (part == 0) sRow[el] = r;
      uint4* d4 = (uint4*)(sA + el * LDA + part * 64);
      if (PRECONV) {
        // pure copy: 64 bf16 = 8x uint4, no conversion VALU
        const unsigned short* src =
            (part < 2 ? hqb + (size_t)r * DD : hkvb + (size_t)c * DD) + (part & 1) * 64;
        const uint4* s4 = (const uint4*)src;
#pragma unroll
        for (int i = 0; i < 8; ++i) d4[i] = s4[i];
      } else {
        const float* src =
            (part < 2 ? h_q + (size_t)r * DD : h_kv + (size_t)c * DD) + (part & 1) * 64;
        const float4* s4 = (const float4*)src;
#pragma unroll
        for (int i = 0; i < 8; ++i) d4[i] = pack8(s4 + 2 * i);
      }
    }
    __syncthreads();

    // ---- layer 1: [64x256] @ We1 ----
    f32x4 acc[4][2];
#pragma unroll
    for (int mt = 0; mt < 4; ++mt)
#pragma unroll
      for (int nt = 0; nt < 2; ++nt) {
        f32x4 z = {0.0f, 0.0f, 0.0f, 0.0f};
        acc[mt][nt] = z;
      }
#pragma unroll
    for (int ks = 0; ks < 8; ++ks) {
#pragma unroll
      for (int mt = 0; mt < 4; ++mt) {
        bf16x8 a = *(const bf16x8*)(sA + (mt * 16 + l16) * LDA + ks * 32 + quad * 8);
        acc[mt][0] = __builtin_amdgcn_mfma_f32_16x16x32_bf16(a, wf1[0][ks], acc[mt][0], 0, 0, 0);
        acc[mt][1] = __builtin_amdgcn_mfma_f32_16x16x32_bf16(a, wf1[1][ks], acc[mt][1], 0, 0, 0);
      }
    }

    // ---- silu -> sT (C-layout: col=l16, row=quad*4+rg) ----
#pragma unroll
    for (int mt = 0; mt < 4; ++mt)
#pragma unroll
      for (int nt = 0; nt < 2; ++nt)
#pragma unroll
        for (int rg = 0; rg < 4; ++rg) {
          float x = silu_f(acc[mt][nt][rg] + bias1[nt]);
          sT[(mt * 16 + quad * 4 + rg) * LDT + wcol + nt * 16 + l16] = f2b(x);
        }
    __syncthreads();

    // ---- layer 2: [64x128] @ We2 ----
    f32x4 acc2[4][2];
#pragma unroll
    for (int mt = 0; mt < 4; ++mt)
#pragma unroll
      for (int nt = 0; nt < 2; ++nt) {
        f32x4 z = {0.0f, 0.0f, 0.0f, 0.0f};
        acc2[mt][nt] = z;
      }
#pragma unroll
    for (int ks = 0; ks < 4; ++ks) {
#pragma unroll
      for (int mt = 0; mt < 4; ++mt) {
        bf16x8 a = *(const bf16x8*)(sT + (mt * 16 + l16) * LDT + ks * 32 + quad * 8);
        acc2[mt][0] = __builtin_amdgcn_mfma_f32_16x16x32_bf16(a, wf2[0][ks], acc2[mt][0], 0, 0, 0);
        acc2[mt][1] = __builtin_amdgcn_mfma_f32_16x16x32_bf16(a, wf2[1][ks], acc2[mt][1], 0, 0, 0);
      }
    }

    // ---- epilogue: mij store (fp32); atomic scatter only in fallback ----
#pragma unroll
    for (int mt = 0; mt < 4; ++mt) {
#pragma unroll
      for (int rg = 0; rg < 4; ++rg) {
        const int m = mt * 16 + quad * 4 + rg;
        const size_t e = (size_t)(e0 + m);
        const int gr = sRow[m];
#pragma unroll
        for (int nt = 0; nt < 2; ++nt) {
          const int n = wcol + nt * 16 + l16;
          float x = silu_f(acc2[mt][nt][rg] + bias2[nt]);
          mij[e * HH + n] = x;
          if (DO_ATOMIC) atomicAdd(&agg[(size_t)gr * HH + n], x);
        }
      }
    }
    __syncthreads();  // protect sA/sRow/sT against next iteration's staging
  }
}

// ---------------- node kernel: out = h_q + silu([h_q|agg]@Wn1+bn1)@Wn2+bn2 ----
__global__ __launch_bounds__(256, 2) void node_kernel(
    const float* __restrict__ h_q,
    const float* __restrict__ agg,
    const float* __restrict__ Wn1,
    const float* __restrict__ bn1,
    const float* __restrict__ Wn2,
    const float* __restrict__ bn2,
    float* __restrict__ out,
    int num_tiles) {
  __shared__ __align__(16) unsigned short sA[BM * LDA];
  __shared__ __align__(16) unsigned short sT[BM * LDT];

  const int tid  = threadIdx.x;
  const int wave = tid >> 6;
  const int lane = tid & 63;
  const int quad = lane >> 4;
  const int l16  = lane & 15;
  const int wcol = wave * 32;

  bf16x8 wf1[2][8];
  bf16x8 wf2[2][4];
  float bias1[2], bias2[2];
#pragma unroll
  for (int nt = 0; nt < 2; ++nt) {
    const int n = wcol + nt * 16 + l16;
    bias1[nt] = bn1[n];
    bias2[nt] = bn2[n];
#pragma unroll
    for (int ks = 0; ks < 8; ++ks) {
      const int kb = ks * 32 + quad * 8;
      bf16x8 v;
#pragma unroll
      for (int j = 0; j < 8; ++j) v[j] = (short)f2b(Wn1[(kb + j) * HH + n]);
      wf1[nt][ks] = v;
    }
#pragma unroll
    for (int ks = 0; ks < 4; ++ks) {
      const int kb = ks * 32 + quad * 8;
      bf16x8 v;
#pragma unroll
      for (int j = 0; j < 8; ++j) v[j] = (short)f2b(Wn2[(kb + j) * HH + n]);
      wf2[nt][ks] = v;
    }
  }

  for (int tile = blockIdx.x; tile < num_tiles; tile += gridDim.x) {
    const int n0 = tile * BM;

    // ---- stage: parts 0/1 = h_q, parts 2/3 = agg (both fp32 -> bf16) ----
    {
      const int el = tid >> 2;
      const int part = tid & 3;
      const int node = n0 + el;
      uint4* d4 = (uint4*)(sA + el * LDA + part * 64);
      if (node < NQ) {
        const float* src =
            (part < 2 ? h_q + (size_t)node * DD : agg + (size_t)node * HH) + (part & 1) * 64;
        const float4* s4 = (const float4*)src;
#pragma unroll
        for (int i = 0; i < 8; ++i) d4[i] = pack8(s4 + 2 * i);
      } else {
        uint4 z = {0u, 0u, 0u, 0u};
#pragma unroll
        for (int i = 0; i < 8; ++i) d4[i] = z;
      }
    }
    __syncthreads();

    f32x4 acc[4][2];
#pragma unroll
    for (int mt = 0; mt < 4; ++mt)
#pragma unroll
      for (int nt = 0; nt < 2; ++nt) {
        f32x4 z = {0.0f, 0.0f, 0.0f, 0.0f};
        acc[mt][nt] = z;
      }
#pragma unroll
    for (int ks = 0; ks < 8; ++ks) {
#pragma unroll
      for (int mt = 0; mt < 4; ++mt) {
        bf16x8 a = *(const bf16x8*)(sA + (mt * 16 + l16) * LDA + ks * 32 + quad * 8);
        acc[mt][0] = __builtin_amdgcn_mfma_f32_16x16x32_bf16(a, wf1[0][ks], acc[mt][0], 0, 0, 0);
        acc[mt][1] = __builtin_amdgcn_mfma_f32_16x16x32_bf16(a, wf1[1][ks], acc[mt][1], 0, 0, 0);
      }
    }

#pragma unroll
    for (int mt = 0; mt < 4; ++mt)
#pragma unroll
      for (int nt = 0; nt < 2; ++nt)
#pragma unroll
        for (int rg = 0; rg < 4; ++rg) {
          float x = silu_f(acc[mt][nt][rg] + bias1[nt]);
          sT[(mt * 16 + quad * 4 + rg) * LDT + wcol + nt * 16 + l16] = f2b(x);
        }
    __syncthreads();

    f32x4 acc2[4][2];
#pragma unroll
    for (int mt = 0; mt < 4; ++mt)
#pragma unroll
      for (int nt = 0; nt < 2; ++nt) {
        f32x4 z = {0.0f, 0.0f, 0.0f, 0.0f};
        acc2[mt][nt] = z;
      }
#pragma unroll
    for (int ks = 0; ks < 4; ++ks) {
#pragma unroll
      for (int mt = 0; mt < 4; ++mt) {
        bf16x8 a = *(const bf16x8*)(sT + (mt * 16 + l16) * LDT + ks * 32 + quad * 8);
        acc2[mt][0] = __builtin_amdgcn_mfma_f32_16x16x32_bf16(a, wf2[0][ks], acc2[mt][0], 0, 0, 0);
        acc2[mt][1] = __builtin_amdgcn_mfma_f32_16x16x32_bf16(a, wf2[1][ks], acc2[mt][1], 0, 0, 0);
      }
    }

    // ---- epilogue: residual add, bias, fp32 store (no silu on layer 2) ----
#pragma unroll
    for (int mt = 0; mt < 4; ++mt) {
#pragma unroll
      for (int rg = 0; rg < 4; ++rg) {
        const int m = mt * 16 + quad * 4 + rg;
        const int node = n0 + m;
        if (node < NQ) {
#pragma unroll
          for (int nt = 0; nt < 2; ++nt) {
            const int n = wcol + nt * 16 + l16;
            float x = acc2[mt][nt][rg] + bias2[nt] + h_q[(size_t)node * DD + n];
            out[(size_t)node * DD + n] = x;
          }
        }
      }
    }
    __syncthreads();
  }
}

extern "C" void kernel_launch(void* const* d_in, const int* in_sizes, int n_in,
                              void* d_out, int out_size, void* d_ws, size_t ws_size,
                              hipStream_t stream) {
  const float* h_q  = (const float*)d_in[0];
  const float* h_kv = (const float*)d_in[1];
  const int* eidx   = (const int*)d_in[2];
  const float* We1  = (const float*)d_in[3];
  const float* be1  = (const float*)d_in[4];
  const float* We2  = (const float*)d_in[5];
  const float* be2  = (const float*)d_in[6];
  const float* Wn1  = (const float*)d_in[7];
  const float* bn1  = (const float*)d_in[8];
  const float* Wn2  = (const float*)d_in[9];
  const float* bn2  = (const float*)d_in[10];

  float* out = (float*)d_out;            // [NQ*DD] h_q_new, then [NE*HH] mij
  float* mij = out + (size_t)NQ * DD;

  // workspace layout (each section 256B-aligned):
  //   agg | offs | cur | cnt | blksum | blkoff | eid | hqb | hkvb
  auto align_up = [](size_t x) { return (x + 255) & ~(size_t)255; };
  char* ws = (char*)d_ws;
  size_t woff = 0;
  float* agg = (float*)(ws + woff);  woff = align_up(woff + (size_t)NQ * HH * sizeof(float));
  int* offs   = (int*)(ws + woff);   woff = align_up(woff + (size_t)(NQ + 1) * sizeof(int));
  int* cur    = (int*)(ws + woff);   woff = align_up(woff + (size_t)NQ * sizeof(int));
  int* cnt    = (int*)(ws + woff);   woff = align_up(woff + (size_t)NQ * sizeof(int));
  int* blksum = (int*)(ws + woff);   woff = align_up(woff + (size_t)NCH * sizeof(int));
  int* blkoff = (int*)(ws + woff);   woff = align_up(woff + (size_t)NCH * sizeof(int));
  int* eid    = (int*)(ws + woff);   woff = align_up(woff + (size_t)NE * sizeof(int));
  const size_t need_csr = woff;
  unsigned short* hqb  = (unsigned short*)(ws + woff);
  woff = align_up(woff + (size_t)NQ * DD * sizeof(unsigned short));
  unsigned short* hkvb = (unsigned short*)(ws + woff);
  woff = align_up(woff + (size_t)NKV * DD * sizeof(unsigned short));
  const size_t need_full = woff;

  const int etiles = NE / BM;              // 10000 exactly
  const int ntiles = (NQ + BM - 1) / BM;   // 313
  const int egrid  = 768;                  // 3 blocks/CU * 256 CUs, persistent

  if (ws_size >= need_full) {
    // ---- full path: pre-converted bf16 gather + deterministic CSR agg ----
    hipMemsetAsync(cnt, 0, (size_t)NQ * sizeof(int), stream);
    conv_kernel<<<(NQ * DD / 8 + 255) / 256, 256, 0, stream>>>(h_q, hqb, NQ * DD / 8);
    conv_kernel<<<(NKV * DD / 8 + 255) / 256, 256, 0, stream>>>(h_kv, hkvb, NKV * DD / 8);
    hist_kernel<<<NE / 256, 256, 0, stream>>>(eidx, cnt);
    scan1_kernel<<<NCH, 256, 0, stream>>>(cnt, offs, blksum);
    scan2_kernel<<<1, 128, 0, stream>>>(blksum, blkoff, offs);
    scan3_kernel<<<NCH, 256, 0, stream>>>(offs, cur, blkoff);
    scatter_kernel<<<NE / 256, 256, 0, stream>>>(eidx, cur, eid);
    edge_kernel<true, false><<<egrid, 256, 0, stream>>>(
        h_q, h_kv, hqb, hkvb, eidx, eidx + NE, We1, be1, We2, be2, mij, agg, etiles);
    agg_kernel<<<(NQ * 64) / 256, 256, 0, stream>>>(mij, offs, eid, agg);
    node_kernel<<<ntiles, 256, 0, stream>>>(h_q, agg, Wn1, bn1, Wn2, bn2, out, ntiles);
  } else if (ws_size >= need_csr) {
    // ---- CSR path without preconv ----
    hipMemsetAsync(cnt, 0, (size_t)NQ * sizeof(int), stream);
    hist_kernel<<<NE / 256, 256, 0, stream>>>(eidx, cnt);
    scan1_kernel<<<NCH, 256, 0, stream>>>(cnt, offs, blksum);
    scan2_kernel<<<1, 128, 0, stream>>>(blksum, blkoff, offs);
    scan3_kernel<<<NCH, 256, 0, stream>>>(offs, cur, blkoff);
    scatter_kernel<<<NE / 256, 256, 0, stream>>>(eidx, cur, eid);
    edge_kernel<false, false><<<egrid, 256, 0, stream>>>(
        h_q, h_kv, nullptr, nullptr, eidx, eidx + NE, We1, be1, We2, be2, mij, agg, etiles);
    agg_kernel<<<(NQ * 64) / 256, 256, 0, stream>>>(mij, offs, eid, agg);
    node_kernel<<<ntiles, 256, 0, stream>>>(h_q, agg, Wn1, bn1, Wn2, bn2, out, ntiles);
  } else {
    // ---- fallback: previously-verified fp32-atomic path ----
    hipMemsetAsync(agg, 0, (size_t)NQ * HH * sizeof(float), stream);
    edge_kernel<false, true><<<egrid, 256, 0, stream>>>(
        h_q, h_kv, nullptr, nullptr, eidx, eidx + NE, We1, be1, We2, be2, mij, agg, etiles);
    node_kernel<<<ntiles, 256, 0, stream>>>(h_q, agg, Wn1, bn1, Wn2, bn2, out, ntiles);
  }
}